// Round 10
// baseline (426.509 us; speedup 1.0000x reference)
//
#include <hip/hip_runtime.h>

#define VOCAB 8192
#define DIM   256
#define NTOK  32768          // 8*4096

// d_out layout (floats): quantised[8388608], loss, codebook_loss, idx[32768] (as float)
#define LOSS_OFF 8388608
#define CB_OFF   8388609
#define IDX_OFF  8388610

// ---- ws layout (bytes) ----
#define X2_F     0            // float[32768]   (f32 index)
#define E2_F     32768        // float[8192]
#define ACC_F    40960        // float
#define CNT_I    40961        // int
#define OVF_I    40962        // int
#define BEST_B   196608       // u64[32768]   -> ends 458752
#define EMB16_B  458752       // bf16[8192*256] = 4 MiB -> ends 4653056
#define SMAX_B   4718592      // float[256][32768] = 32 MiB (also reused as binned list)
#define SCNT_B   38273024     // int[256]
#define SBASE_B  38274048     // int[256]
#define SCUR_B   38275072     // int[256]
#define LIST_B   38404096     // u32[CAP]
#define CAP      4194304
#define WS_NEED  (LIST_B + CAP * 4)   // 55,181,312 bytes

#define M2 1.5e-4f            // dot-space rescue margin (err budget ~6e-5 practical)
#define LCAP 16000            // per-block LDS candidate cap (256*16000 < CAP)

typedef __attribute__((ext_vector_type(8)))  short bf16x8;
typedef __attribute__((ext_vector_type(16))) float f32x16;

// ===========================================================================
// k_sums: numpy pairwise-exact x2/e2 (proven round 3) + init scalars/best/scnt
__global__ __launch_bounds__(256) void k_sums(const float* __restrict__ x,
                                              const float* __restrict__ emb,
                                              float* __restrict__ ws,
                                              unsigned long long* __restrict__ best,
                                              int* __restrict__ scnt,
                                              int full) {
    const int lane = threadIdx.x & 63;
    const int wave = threadIdx.x >> 6;
    const int row  = blockIdx.x * 16 + wave * 4 + (lane >> 4);
    const int sub  = lane & 15;
    const int k    = sub & 7;
    const int half = sub >> 3;
    const float* src = (row < NTOK ? x + (size_t)row * DIM
                                   : emb + (size_t)(row - NTOK) * DIM)
                       + half * 128 + k;
    float r;
    {
        float v0 = src[0];
        float t0 = v0 * v0;
        asm volatile("" : "+v"(t0));     // block fma contraction
        r = t0;
        for (int i = 1; i < 16; ++i) {
            float w = src[8 * i];
            float u = w * w;
            asm volatile("" : "+v"(u));
            r = r + u;
        }
    }
    float t;
    t = __shfl_xor(r, 1, 64); r = r + t;
    t = __shfl_xor(r, 2, 64); r = r + t;
    t = __shfl_xor(r, 4, 64); r = r + t;
    t = __shfl_xor(r, 8, 64); r = r + t;
    if (sub == 0) ws[row] = r;
    const int gid = blockIdx.x * 256 + threadIdx.x;
    if (gid == 0) {
        ws[ACC_F] = 0.0f;
        ((int*)ws)[CNT_I] = 0;
        ((int*)ws)[OVF_I] = 0;
    }
    if (full) {
        if (gid < NTOK) best[gid] = ~0ULL;
        if (gid < 256)  scnt[gid] = 0;
    }
}

// ===========================================================================
// k_cvt: emb fp32 -> bf16 (truncate; margin absorbs the bias)
__global__ __launch_bounds__(256) void k_cvt(const float* __restrict__ emb,
                                             unsigned* __restrict__ out) {
    const int i = blockIdx.x * 256 + threadIdx.x;      // 524288 threads x 4 floats
    const float4 f = *(const float4*)(emb + (size_t)i * 4);
    unsigned b0 = __float_as_uint(f.x), b1 = __float_as_uint(f.y);
    unsigned b2 = __float_as_uint(f.z), b3 = __float_as_uint(f.w);
    uint2 o;
    o.x = (b1 & 0xFFFF0000u) | (b0 >> 16);
    o.y = (b3 & 0xFFFF0000u) | (b2 >> 16);
    *(uint2*)(out + (size_t)i * 2) = o;
}

// ===========================================================================
// k_coarse v2: 1024 threads, 16 waves = (tq 0..3 token-quarters) x (csub 0..3
// code-slices). Per wave: 32 tokens in regs (bx[16] = 64 VGPR, af-reuse=1),
// 16 MFMA/chunk. 4 waves/SIMD (launch_bounds 1024,4) -> TLP hides LDS/latency.
// 5-bit XOR swizzle both sides (round-7 proven); counted vmcnt(4) excludes
// the smax store; 2 barriers/chunk.
#define AS1 __attribute__((address_space(1)))
#define AS3 __attribute__((address_space(3)))

#define STAGE4(BUFI, N) do {                                                   \
    const char* _src = (const char*)embh + ((size_t)(N) << 16);                \
    char* _dst = ebuf[BUFI];                                                   \
    _Pragma("unroll")                                                          \
    for (int _r = 0; _r < 4; ++_r) {                                           \
        const unsigned _o = (unsigned)tid * 16u + (unsigned)_r * 16384u;       \
        __builtin_amdgcn_global_load_lds(                                      \
            (const AS1 void*)(_src + so4[_r]),                                 \
            (AS3 void*)(_dst + _o), 16, 0, 0);                                 \
    }                                                                          \
} while (0)

__device__ __forceinline__ unsigned f_ord(float v) {
    unsigned u = __float_as_uint(v);
    return u ^ ((unsigned)((int)u >> 31) | 0x80000000u);
}
__device__ __forceinline__ float f_unord(unsigned k) {
    unsigned m = (k >> 31) ? 0x80000000u : 0xFFFFFFFFu;
    return __uint_as_float(k ^ m);
}

__global__ __launch_bounds__(1024, 4) void k_coarse(
        const float* __restrict__ x, const unsigned short* __restrict__ embh,
        float* __restrict__ smax,
        unsigned* __restrict__ list, int* __restrict__ cnt,
        int* __restrict__ ovf) {
    __shared__ char ebuf[2][65536];          // 2 x 128 codes x 512 B
    __shared__ unsigned tmax[128];
    __shared__ float tthr[128];
    __shared__ unsigned gbase, bcnt;

    const int tid  = threadIdx.x;
    const int lane = tid & 63, wid = tid >> 6;
    const int tq = wid & 3, csub = wid >> 2;
    const int tok0 = blockIdx.x * 128 + tq * 32;

    // hoisted swizzled staging source offsets (loop-invariant)
    unsigned so4[4];
#pragma unroll
    for (int r = 0; r < 4; ++r) {
        const unsigned o = (unsigned)tid * 16u + (unsigned)r * 16384u;
        so4[r] = (o & ~511u) | ((o & 511u) ^ (((o >> 9) & 31u) << 4));
    }

    // ---- persistent x B-frags: bx[kt] for 32 tokens; col = lane&31,
    //      k = kt*16 + (lane>>5)*8 + j
    bf16x8 bx[16];
    {
        const float* xr = x + (size_t)(tok0 + (lane & 31)) * DIM + (lane >> 5) * 8;
#pragma unroll
        for (int kt = 0; kt < 16; ++kt) {
            float4 f0 = *(const float4*)(xr + kt * 16);
            float4 f1 = *(const float4*)(xr + kt * 16 + 4);
            union { bf16x8 v; unsigned u[4]; } P;
            P.u[0] = (__float_as_uint(f0.y) & 0xFFFF0000u) | (__float_as_uint(f0.x) >> 16);
            P.u[1] = (__float_as_uint(f0.w) & 0xFFFF0000u) | (__float_as_uint(f0.z) >> 16);
            P.u[2] = (__float_as_uint(f1.y) & 0xFFFF0000u) | (__float_as_uint(f1.x) >> 16);
            P.u[3] = (__float_as_uint(f1.w) & 0xFFFF0000u) | (__float_as_uint(f1.z) >> 16);
            bx[kt] = P.v;
        }
    }

    // A-read: row rl = csub*32 + lane&31, col bytes = kt*32 + (lane>>5)*16
    const unsigned rl    = (unsigned)(csub * 32 + (lane & 31));
    const unsigned abase = rl * 512u + (unsigned)((lane >> 5) * 16);
    const unsigned sw    = (rl & 31u) << 4;     // 5-bit XOR: 32 distinct slots

    STAGE4(0, 0);
    asm volatile("s_waitcnt vmcnt(0)" ::: "memory");
    __builtin_amdgcn_s_barrier();

    float rmax = -3.0e38f;
    for (int n = 0; n < 64; ++n) {
        const char* cb = ebuf[n & 1];
        const bool  more = (n + 1 < 64);

        if (more) {
            STAGE4((n + 1) & 1, n + 1);
            // retire stage(n)+old store; stage(n+1)'s 4 loads stay in flight
            asm volatile("s_waitcnt vmcnt(4)" ::: "memory");
        } else {
            asm volatile("s_waitcnt vmcnt(0)" ::: "memory");
        }
        __builtin_amdgcn_s_barrier();       // buf[n&1] fully staged (all waves)
        asm volatile("" ::: "memory");

        f32x16 acc;
#pragma unroll
        for (int q = 0; q < 16; ++q) acc[q] = 0.0f;

#pragma unroll
        for (int b4 = 0; b4 < 4; ++b4) {
            bf16x8 a0 = *(const bf16x8*)(cb + ((abase + (unsigned)(b4 * 4 + 0) * 32u) ^ sw));
            bf16x8 a1 = *(const bf16x8*)(cb + ((abase + (unsigned)(b4 * 4 + 1) * 32u) ^ sw));
            bf16x8 a2 = *(const bf16x8*)(cb + ((abase + (unsigned)(b4 * 4 + 2) * 32u) ^ sw));
            bf16x8 a3 = *(const bf16x8*)(cb + ((abase + (unsigned)(b4 * 4 + 3) * 32u) ^ sw));
            __builtin_amdgcn_s_setprio(1);
            acc = __builtin_amdgcn_mfma_f32_32x32x16_bf16(a0, bx[b4 * 4 + 0], acc, 0, 0, 0);
            acc = __builtin_amdgcn_mfma_f32_32x32x16_bf16(a1, bx[b4 * 4 + 1], acc, 0, 0, 0);
            acc = __builtin_amdgcn_mfma_f32_32x32x16_bf16(a2, bx[b4 * 4 + 2], acc, 0, 0, 0);
            acc = __builtin_amdgcn_mfma_f32_32x32x16_bf16(a3, bx[b4 * 4 + 3], acc, 0, 0, 0);
            __builtin_amdgcn_s_setprio(0);
        }

        // per-lane max over 16 code-rows, then merge the two code-halves
        float m0;
        {
            float a = fmaxf(fmaxf(acc[0], acc[1]),  fmaxf(acc[2], acc[3]));
            float b = fmaxf(fmaxf(acc[4], acc[5]),  fmaxf(acc[6], acc[7]));
            float c = fmaxf(fmaxf(acc[8], acc[9]),  fmaxf(acc[10], acc[11]));
            float d = fmaxf(fmaxf(acc[12], acc[13]),fmaxf(acc[14], acc[15]));
            m0 = fmaxf(fmaxf(a, b), fmaxf(c, d));
        }
        m0 = fmaxf(m0, __shfl_xor(m0, 32, 64));   // token = tok0 + (lane&31)
        rmax = fmaxf(rmax, m0);
        if (lane < 32)
            smax[(size_t)(n * 4 + csub) * NTOK + tok0 + lane] = m0;

        asm volatile("" ::: "memory");
        __builtin_amdgcn_s_barrier();       // all reads of buf[n&1] done
    }

    // ---- per-token threshold = gmax - M2 (cross-wave merge in LDS)
    unsigned* lbuf = (unsigned*)ebuf;          // main loop done: reuse as list
    if (tid < 128) tmax[tid] = 0u;
    if (tid == 0) { lbuf[0] = 0u; }
    __syncthreads();
    if (lane < 32) atomicMax(&tmax[tq * 32 + lane], f_ord(rmax));
    __syncthreads();
    if (tid < 128) tthr[tid] = f_unord(tmax[tid]) - M2;
    __syncthreads();

    // ---- fused collect: re-read own smax slice, compact in LDS
    const int t0b = blockIdx.x * 128;
    for (int r = 0; r < 32; ++r) {
        const int cell  = r * 1024 + tid;      // 0..32767
        const int stile = cell >> 7, tl = cell & 127;
        const float v = smax[(size_t)stile * NTOK + t0b + tl];
        if (v >= tthr[tl]) {
            const unsigned p = atomicAdd(&lbuf[0], 1u);
            if (p < LCAP)
                lbuf[2 + p] = ((unsigned)(t0b + tl) << 8) | (unsigned)stile;
        }
    }
    __syncthreads();
    if (tid == 0) {
        unsigned bc = lbuf[0];
        if (bc > LCAP) { bc = LCAP; *ovf = 1; }
        bcnt  = bc;
        gbase = (unsigned)atomicAdd(cnt, (int)bc);   // ONE global atomic per block
    }
    __syncthreads();
    const unsigned bc = bcnt, gb = gbase;
    for (unsigned i = tid; i < bc; i += 1024) list[gb + i] = lbuf[2 + i];
}

// ===========================================================================
// Binning: count per stile -> scan -> scatter into per-stile buckets
__global__ __launch_bounds__(256) void k_bincount(const unsigned* __restrict__ list,
                                                  const int* __restrict__ cnt,
                                                  int* __restrict__ scnt) {
    __shared__ int lc[256];
    lc[threadIdx.x] = 0;
    __syncthreads();
    int n = *cnt; if (n > CAP) n = CAP;
    for (int i = blockIdx.x * 256 + threadIdx.x; i < n; i += 64 * 256)
        atomicAdd(&lc[list[i] & 255u], 1);
    __syncthreads();
    if (lc[threadIdx.x]) atomicAdd(&scnt[threadIdx.x], lc[threadIdx.x]);
}

__global__ __launch_bounds__(256) void k_scan(const int* __restrict__ scnt,
                                              int* __restrict__ sbase,
                                              int* __restrict__ scur) {
    __shared__ int a[256], b[256];
    const int t = threadIdx.x;
    a[t] = scnt[t];
    __syncthreads();
    int* src = a; int* dst = b;
    for (int off = 1; off < 256; off <<= 1) {
        dst[t] = src[t] + ((t >= off) ? src[t - off] : 0);
        __syncthreads();
        int* tp = src; src = dst; dst = tp;
    }
    const int excl = src[t] - scnt[t];
    sbase[t] = excl;
    scur[t]  = excl;
}

__global__ __launch_bounds__(256) void k_scatter(const unsigned* __restrict__ list,
                                                 const int* __restrict__ cnt,
                                                 int* __restrict__ scur,
                                                 unsigned* __restrict__ binned) {
    int n = *cnt; if (n > CAP) n = CAP;
    for (int i = blockIdx.x * 256 + threadIdx.x; i < n; i += 64 * 256) {
        const unsigned e = list[i];
        const int p = atomicAdd(&scur[e & 255u], 1);
        binned[p] = e;
    }
}

// ===========================================================================
// k_exact2: per-stile buckets, emb tile in LDS, ref-bit-identical fp32 score
__device__ __forceinline__ float exact_score(const float* __restrict__ xr,
                                             const float* __restrict__ er,
                                             float x2t, float e2v) {
    float dot = 0.0f;
#pragma unroll 16
    for (int d = 0; d < DIM; d += 4) {
        const float4 e4 = *(const float4*)(er + d);
        const float4 x4 = *(const float4*)(xr + d);
        dot = fmaf(e4.x, x4.x, dot);
        dot = fmaf(e4.y, x4.y, dot);
        dot = fmaf(e4.z, x4.z, dot);
        dot = fmaf(e4.w, x4.w, dot);
    }
    const float A = x2t + e2v;          // fl(x2 + e2)
    return A - 2.0f * dot;              // fl(A - fl(2*dot)); 2*dot exact
}

__global__ __launch_bounds__(256) void k_exact2(
        const float* __restrict__ x, const float* __restrict__ emb,
        const float* __restrict__ x2, const float* __restrict__ e2,
        const unsigned* __restrict__ binned, const int* __restrict__ sbase,
        const int* __restrict__ scnt, const int* __restrict__ ovf,
        unsigned long long* __restrict__ best) {
    __shared__ float elds[32][257];
    __shared__ float e2s[32];
    const int s = blockIdx.x >> 3, sub = blockIdx.x & 7;
    {   // stage this stile's 32 emb rows (fp32) into LDS
        const int r = threadIdx.x >> 3, c0 = (threadIdx.x & 7) * 32;
        const float* er = emb + (size_t)(s * 32 + r) * DIM + c0;
#pragma unroll
        for (int q = 0; q < 8; ++q) {
            const float4 f = *(const float4*)(er + q * 4);
            elds[r][c0 + q * 4 + 0] = f.x; elds[r][c0 + q * 4 + 1] = f.y;
            elds[r][c0 + q * 4 + 2] = f.z; elds[r][c0 + q * 4 + 3] = f.w;
        }
        if (threadIdx.x < 32) e2s[threadIdx.x] = e2[s * 32 + threadIdx.x];
    }
    __syncthreads();

    const int lane = threadIdx.x & 63, wave = threadIdx.x >> 6;
    const int l5 = lane & 31, half = lane >> 5;
    const int base = sbase[s], count = scnt[s];
    const float e2v = e2s[l5];

    for (int k = (sub * 4 + wave) * 2 + half; k < count; k += 64) {
        const unsigned e = binned[base + k];
        const int token  = (int)(e >> 8);
        const float* xr  = x + (size_t)token * DIM;
        const float x2t  = x2[token];
        // sequential fmaf chain, d ascending, x/y/z/w order == proven ref semantics
        float dot = 0.0f;
#pragma unroll 16
        for (int d = 0; d < DIM; d += 4) {
            const float4 x4 = *(const float4*)(xr + d);
            dot = fmaf(elds[l5][d + 0], x4.x, dot);
            dot = fmaf(elds[l5][d + 1], x4.y, dot);
            dot = fmaf(elds[l5][d + 2], x4.z, dot);
            dot = fmaf(elds[l5][d + 3], x4.w, dot);
        }
        const float A  = x2t + e2v;
        const float sc = A - 2.0f * dot;
        unsigned long long pk =
            ((unsigned long long)__float_as_uint(sc) << 32) | (unsigned)(s * 32 + l5);
#pragma unroll
        for (int m = 1; m < 32; m <<= 1) {   // stays within the 32-lane half
            unsigned long long o = __shfl_xor(pk, m, 64);
            if (o < pk) pk = o;
        }
        if (l5 == 0) atomicMin(&best[token], pk);
    }

    if (*ovf) {   // exhaustive safety net (never expected)
        const size_t stride = (size_t)2048 * 256;
        for (size_t c = blockIdx.x * 256 + threadIdx.x;
             c < (size_t)NTOK * VOCAB; c += stride) {
            const int token = (int)(c >> 13);
            const int v     = (int)(c & (VOCAB - 1));
            const float sc = exact_score(x + (size_t)token * DIM, emb + (size_t)v * DIM,
                                         x2[token], e2[v]);
            unsigned long long pk =
                ((unsigned long long)__float_as_uint(sc) << 32) | (unsigned)v;
            atomicMin(&best[token], pk);
        }
    }
}

__global__ __launch_bounds__(256) void k_idx(const unsigned long long* __restrict__ best,
                                             float* __restrict__ idxf) {
    const int t = blockIdx.x * 256 + threadIdx.x;
    idxf[t] = (float)(unsigned)(best[t] & 0xFFFFFFFFULL);
}

// ===========================================================================
// FALLBACK (round-3 proven path) — used when ws_size < WS_NEED
__global__ __launch_bounds__(512) void k_main_fb(
        const float* __restrict__ x, const float* __restrict__ emb,
        const float* __restrict__ x2, const float* __restrict__ e2,
        float* __restrict__ idxf) {
    __shared__ float xT[32][132];
    __shared__ float eT[32][260];
    const int tid = threadIdx.x;
    const int tx = tid & 31, ty = tid >> 5;
    const int t0 = blockIdx.x * 128;
    float x2r[8];
#pragma unroll
    for (int ii = 0; ii < 8; ++ii)
        x2r[ii] = x2[t0 + ((ii & 4) << 4) + ty * 4 + (ii & 3)];
    float tb[8]; int ti[8];
#pragma unroll
    for (int s = 0; s < 8; ++s) { tb[s] = 3.0e38f; ti[s] = 0; }
    const int xt = tid & 127, xc = tid >> 7;
    const int ev = tid & 255, ec0 = tid >> 8;
    for (int v0 = 0; v0 < VOCAB; v0 += 256) {
        float a[8][8];
#pragma unroll
        for (int i = 0; i < 8; ++i)
#pragma unroll
            for (int j = 0; j < 8; ++j) a[i][j] = 0.0f;
        for (int kk = 0; kk < DIM; kk += 32) {
            __syncthreads();
#pragma unroll
            for (int h = 0; h < 2; ++h) {
                const int kc = h * 16 + xc * 4;
                const float4 vx = *(const float4*)&x[(size_t)(t0 + xt) * DIM + kk + kc];
                xT[kc + 0][xt] = vx.x; xT[kc + 1][xt] = vx.y;
                xT[kc + 2][xt] = vx.z; xT[kc + 3][xt] = vx.w;
            }
#pragma unroll
            for (int h = 0; h < 4; ++h) {
                const int kc = (ec0 + 2 * h) * 4;
                const float4 ve = *(const float4*)&emb[(size_t)(v0 + ev) * DIM + kk + kc];
                eT[kc + 0][ev] = ve.x; eT[kc + 1][ev] = ve.y;
                eT[kc + 2][ev] = ve.z; eT[kc + 3][ev] = ve.w;
            }
            __syncthreads();
#pragma unroll 4
            for (int k = 0; k < 32; ++k) {
                float xa[8], eb[8];
                *(float4*)&xa[0] = *(const float4*)&xT[k][ty * 4];
                *(float4*)&xa[4] = *(const float4*)&xT[k][64 + ty * 4];
                *(float4*)&eb[0] = *(const float4*)&eT[k][tx * 4];
                *(float4*)&eb[4] = *(const float4*)&eT[k][128 + tx * 4];
#pragma unroll
                for (int i = 0; i < 8; ++i)
#pragma unroll
                    for (int j = 0; j < 8; ++j)
                        a[i][j] = fmaf(xa[i], eb[j], a[i][j]);
            }
        }
#pragma unroll
        for (int jj = 0; jj < 8; ++jj) {
            const int v = v0 + ((jj & 4) << 5) + tx * 4 + (jj & 3);
            const float evv = e2[v];
#pragma unroll
            for (int ii = 0; ii < 8; ++ii) {
                const float A  = x2r[ii] + evv;
                const float sc = A - 2.0f * a[ii][jj];
                if (sc < tb[ii]) { tb[ii] = sc; ti[ii] = v; }
            }
        }
    }
#pragma unroll
    for (int ii = 0; ii < 8; ++ii) {
        float b = tb[ii]; int bi = ti[ii];
#pragma unroll
        for (int m = 1; m < 32; m <<= 1) {
            const float ob = __shfl_xor(b, m, 64);
            const int   oi = __shfl_xor(bi, m, 64);
            if (ob < b || (ob == b && oi < bi)) { b = ob; bi = oi; }
        }
        if (tx == 0) {
            const int token = t0 + ((ii & 4) << 4) + ty * 4 + (ii & 3);
            idxf[token] = (float)bi;
        }
    }
}

// ===========================================================================
// gather quantised + loss reduction (shared by both paths)
__global__ __launch_bounds__(256) void k_gather(
        const float* __restrict__ x, const float* __restrict__ emb,
        const float* __restrict__ idxf, float* __restrict__ qout,
        float* __restrict__ acc) {
    const int token = blockIdx.x * 4 + (threadIdx.x >> 6);
    const int lane  = threadIdx.x & 63;
    const int v = (int)idxf[token];
    const float4 e4 = *(const float4*)&emb[(size_t)v * DIM + lane * 4];
    const float4 x4 = *(const float4*)&x[(size_t)token * DIM + lane * 4];
    *(float4*)&qout[(size_t)token * DIM + lane * 4] = e4;
    const float dx = e4.x - x4.x, dy = e4.y - x4.y, dz = e4.z - x4.z, dw = e4.w - x4.w;
    float s = dx*dx + dy*dy + dz*dz + dw*dw;
#pragma unroll
    for (int m = 1; m < 64; m <<= 1) s += __shfl_xor(s, m, 64);
    __shared__ float wsum[4];
    if (lane == 0) wsum[threadIdx.x >> 6] = s;
    __syncthreads();
    if (threadIdx.x == 0) atomicAdd(acc, wsum[0] + wsum[1] + wsum[2] + wsum[3]);
}

__global__ void k_final(const float* __restrict__ acc, float* __restrict__ out) {
    const float cb = *acc * (1.0f / 8388608.0f);
    out[LOSS_OFF] = 1.25f * cb;
    out[CB_OFF]   = cb;
}

// ===========================================================================
extern "C" void kernel_launch(void* const* d_in, const int* in_sizes, int n_in,
                              void* d_out, int out_size, void* d_ws, size_t ws_size,
                              hipStream_t stream) {
    const float* x   = (const float*)d_in[0];
    const float* emb = (const float*)d_in[1];
    float* out  = (float*)d_out;
    char*  wsB  = (char*)d_ws;
    float* wsF  = (float*)d_ws;

    float* x2   = wsF + X2_F;
    float* e2   = wsF + E2_F;
    float* acc  = wsF + ACC_F;
    int*   cnt  = (int*)wsF + CNT_I;
    int*   ovf  = (int*)wsF + OVF_I;
    unsigned long long* best = (unsigned long long*)(wsB + BEST_B);
    unsigned short*     e16  = (unsigned short*)(wsB + EMB16_B);
    float*              smax = (float*)(wsB + SMAX_B);
    unsigned*           binned = (unsigned*)(wsB + SMAX_B);   // reuse after collect
    int*                scnt  = (int*)(wsB + SCNT_B);
    int*                sbase = (int*)(wsB + SBASE_B);
    int*                scur  = (int*)(wsB + SCUR_B);
    unsigned*           list  = (unsigned*)(wsB + LIST_B);
    float* idxf = out + IDX_OFF;

    const int full = (ws_size >= (size_t)WS_NEED) ? 1 : 0;

    k_sums<<<(NTOK + VOCAB) / 16, 256, 0, stream>>>(x, emb, wsF, best, scnt, full);
    if (full) {
        k_cvt     <<<2048, 256, 0, stream>>>(emb, (unsigned*)e16);
        k_coarse  <<<256, 1024, 0, stream>>>(x, e16, smax, list, cnt, ovf);
        k_bincount<<<64, 256, 0, stream>>>(list, cnt, scnt);
        k_scan    <<<1, 256, 0, stream>>>(scnt, sbase, scur);
        k_scatter <<<64, 256, 0, stream>>>(list, cnt, scur, binned);
        k_exact2  <<<2048, 256, 0, stream>>>(x, emb, x2, e2, binned, sbase, scnt, ovf, best);
        k_idx     <<<NTOK / 256, 256, 0, stream>>>(best, idxf);
    } else {
        k_main_fb<<<NTOK / 128, 512, 0, stream>>>(x, emb, x2, e2, idxf);
    }
    k_gather<<<NTOK / 4, 256, 0, stream>>>(x, emb, idxf, out, acc);
    k_final <<<1, 1, 0, stream>>>(acc, out);
}